// Round 1
// 427.755 us; speedup vs baseline: 1.0165x; 1.0165x over previous
//
#include <hip/hip_runtime.h>

// LSTM: B=4096, T=2048, I=4, H=3, gates i,f,g,o (W rows r = g*3 + u)
// R4: latency-bound serial chain (1 wave/SIMD, VALUBusy 21%). Replace the
//     3x ds_swizzle h-gather (LDS pipe, ~120cy) with DPP row_ror:{4,8,12}
//     (VALU pipe, ~4-8cy): row_ror:N -> lane i reads lane (i-N)&15, so
//     slot j sources quad (q-j)&3. Also carry cc = 2*log2e*c and emit the
//     g gate pre-scaled so tanh(c) needs no pre-scale mul on the chain.
// R3: 16 lanes per sequence. quad q = unit (q==3 dups unit 2, never consumed
//     with nonzero weight), lane-in-quad s = gate. Gate broadcast: quad_perm.
//     Tail zeroing fused.

#define BB 4096
#define TT 2048
#define L2E 1.4426950408889634f

template<int CTRL>
__device__ __forceinline__ float dppf(float v) {
    return __int_as_float(
        __builtin_amdgcn_update_dpp(0, __float_as_int(v), CTRL, 0xF, 0xF, true));
}

__global__ __launch_bounds__(64, 1) void lstm_seq(
    const float* __restrict__ x, const float* __restrict__ Wih,
    const float* __restrict__ Whh, const float* __restrict__ bih,
    const float* __restrict__ bhh, const int* __restrict__ len,
    float* __restrict__ out)
{
    const int lane  = threadIdx.x & 63;
    const int s     = lane & 3;          // gate: 0=i,1=f,2=g,3=o
    const int q     = (lane >> 2) & 3;   // quad = unit (3 = dup of unit 2)
    const int row16 = lane >> 4;         // sequence within wave (4 per wave)
    const int b     = blockIdx.x * 4 + row16;
    const int u     = (q < 3) ? q : 2;
    const int wrow  = s * 3 + u;

    // Activation via r = rcp(1+exp2(a)), a = pre*scale:
    //   sigmoid (s!=2): scale=-log2e,  act = r
    //   tanh    (s==2): scale=+2log2e, act = 2L2E - 4L2E*r  (pre-scaled g!)
    // Cell state carried as cc = 2*log2e*c, so tanh(c) = fma(-2, rcp(1+exp2(cc)), 1).
    const float scale = (s == 2) ? (2.f * L2E) : (-L2E);
    const float Aa = (s == 2) ? (2.f * L2E) : 0.f;
    const float Bb = (s == 2) ? (-4.f * L2E) : 1.f;

    const float xw0 = Wih[wrow * 4 + 0] * scale;
    const float xw1 = Wih[wrow * 4 + 1] * scale;
    const float xw2 = Wih[wrow * 4 + 2] * scale;
    const float xw3 = Wih[wrow * 4 + 3] * scale;
    const float bias = (bih[wrow] + bhh[wrow]) * scale;

    // h slot j arrives via row_ror:(4j): source quad (q - j) & 3.
    // Zero weight for the dup-quad source.
    float wh[4];
    #pragma unroll
    for (int j = 0; j < 4; ++j) {
        const int srcq = (q - j) & 3;
        wh[j] = (srcq == 3) ? 0.f : Whh[wrow * 3 + srcq] * scale;
    }

    const int mylen = len[b];
    int wmax = mylen;
    #pragma unroll
    for (int off = 1; off < 64; off <<= 1)
        wmax = max(wmax, __shfl_xor(wmax, off));
    const int Tloop = (wmax + 7) & ~7;

    float myh = 0.f, cc = 0.f;
    const float4* __restrict__ xrow = ((const float4*)x) + (size_t)b * TT;
    float* __restrict__ orow = out + (size_t)b * (TT * 3);
    const bool writer = (s == 0) && (q < 3);

    float4 buf[8];
    float xacc[8];
    #pragma unroll
    for (int uu = 0; uu < 8; ++uu) buf[uu] = xrow[uu];

    for (int tb = 0; tb < Tloop; tb += 8) {
        #pragma unroll
        for (int uu = 0; uu < 8; ++uu) {
            const float4 xv = buf[uu];
            xacc[uu] = fmaf(xw3, xv.w, fmaf(xw2, xv.z,
                       fmaf(xw1, xv.y, fmaf(xw0, xv.x, bias))));
        }
        #pragma unroll
        for (int uu = 0; uu < 8; ++uu) {
            const int tn = tb + 8 + uu;
            buf[uu] = xrow[tn < TT ? tn : 0];
        }
        #pragma unroll
        for (int uu = 0; uu < 8; ++uu) {
            const int t = tb + uu;
            // h gather: VALU-pipe DPP row rotates (row = 16 lanes).
            const float hs1 = dppf<0x124>(myh);   // row_ror:4  -> quad q-1
            const float hs2 = dppf<0x128>(myh);   // row_ror:8  -> quad q-2
            const float hs3 = dppf<0x12C>(myh);   // row_ror:12 -> quad q-3
            const float a = fmaf(wh[3], hs3, fmaf(wh[2], hs2,
                            fmaf(wh[1], hs1, fmaf(wh[0], myh, xacc[uu]))));
            const float r = __builtin_amdgcn_rcpf(1.f + __builtin_amdgcn_exp2f(a));
            const float act = fmaf(Bb, r, Aa);
            const float gi = dppf<0x00>(act);   // lane 0 of quad: gate i
            const float gf = dppf<0x55>(act);   // gate f
            const float gg = dppf<0xAA>(act);   // gate g (pre-scaled tanh)
            const float go = dppf<0xFF>(act);   // gate o
            cc = fmaf(gf, cc, gi * gg);         // cc = 2L2E * c
            const float tcv = fmaf(-2.f,
                __builtin_amdgcn_rcpf(1.f + __builtin_amdgcn_exp2f(cc)), 1.f);
            myh = go * tcv;
            if (writer) orow[t * 3 + q] = (t < mylen) ? myh : 0.f;
        }
    }

    // Zero the remaining tail t in [Tloop, TT) for this wave's 4 rows.
    const int start4 = Tloop * 3 / 4;          // multiple of 6, 16B-aligned
    #pragma unroll
    for (int rr = 0; rr < 4; ++rr) {
        float4* __restrict__ o4 = (float4*)(out + ((size_t)(blockIdx.x * 4 + rr)) * (TT * 3));
        for (int idx = start4 + lane; idx < TT * 3 / 4; idx += 64)
            o4[idx] = make_float4(0.f, 0.f, 0.f, 0.f);
    }
}

extern "C" void kernel_launch(void* const* d_in, const int* in_sizes, int n_in,
                              void* d_out, int out_size, void* d_ws, size_t ws_size,
                              hipStream_t stream) {
    const float* x    = (const float*)d_in[0];
    const float* Wih  = (const float*)d_in[1];
    const float* Whh  = (const float*)d_in[2];
    const float* bih  = (const float*)d_in[3];
    const float* bhh  = (const float*)d_in[4];
    const int*   lenp = (const int*)d_in[5];
    float* out = (float*)d_out;

    lstm_seq<<<BB / 4, 64, 0, stream>>>(x, Wih, Whh, bih, bhh, lenp, out);
}